// Round 5
// baseline (339.333 us; speedup 1.0000x reference)
//
#include <hip/hip_runtime.h>

#define N_NODES 50000
#define N_EDGES 625000
#define FEAT 128
#define NEG_SLOPE 0.2f
#define NB_SCAN 196   // ceil(50000/256)

typedef __attribute__((ext_vector_type(8))) short bf16x8;
typedef __attribute__((ext_vector_type(4))) float f32x4;

__device__ __forceinline__ unsigned short f2bf(float f) {
  unsigned u = __float_as_uint(f);
  u += 0x7fffu + ((u >> 16) & 1u);        // round-to-nearest-even
  return (unsigned short)(u >> 16);
}
__device__ __forceinline__ float bf2f(unsigned short s) {
  return __uint_as_float(((unsigned)s) << 16);
}

// ---------------- CSR build ----------------

__global__ __launch_bounds__(256) void hist_kernel(const int* __restrict__ dst,
                                                   int* __restrict__ cnt) {
  int e = blockIdx.x * 256 + threadIdx.x;
  if (e < N_EDGES) atomicAdd(&cnt[dst[e]], 1);
}

__global__ __launch_bounds__(256) void scan_part_kernel(const int* __restrict__ cnt,
                                                        int* __restrict__ part) {
  __shared__ int s[256];
  int i = blockIdx.x * 256 + threadIdx.x;
  s[threadIdx.x] = (i < N_NODES) ? cnt[i] : 0;
  __syncthreads();
  for (int o = 128; o > 0; o >>= 1) {
    if (threadIdx.x < o) s[threadIdx.x] += s[threadIdx.x + o];
    __syncthreads();
  }
  if (threadIdx.x == 0) part[blockIdx.x] = s[0];
}

__global__ __launch_bounds__(256) void scan_top_kernel(int* __restrict__ part,
                                                       int* __restrict__ offs) {
  __shared__ int s[256];
  int tid = threadIdx.x;
  int v = (tid < NB_SCAN) ? part[tid] : 0;
  s[tid] = v;
  __syncthreads();
  for (int o = 1; o < 256; o <<= 1) {
    int t = (tid >= o) ? s[tid - o] : 0;
    __syncthreads();
    s[tid] += t;
    __syncthreads();
  }
  if (tid < NB_SCAN) part[tid] = s[tid] - v;  // exclusive scan of block sums
  if (tid == 255) offs[N_NODES] = s[255];     // total (= N_EDGES)
}

__global__ __launch_bounds__(256) void scan_down_kernel(int* __restrict__ cnt,
                                                        const int* __restrict__ part,
                                                        int* __restrict__ offs) {
  __shared__ int s[256];
  int tid = threadIdx.x;
  int i = blockIdx.x * 256 + tid;
  int v = (i < N_NODES) ? cnt[i] : 0;
  s[tid] = v;
  __syncthreads();
  for (int o = 1; o < 256; o <<= 1) {
    int t = (tid >= o) ? s[tid - o] : 0;
    __syncthreads();
    s[tid] += t;
    __syncthreads();
  }
  if (i < N_NODES) {
    int excl = s[tid] - v + part[blockIdx.x];
    offs[i] = excl;
    cnt[i] = excl;  // becomes the fill cursor
  }
}

__global__ __launch_bounds__(256) void fill_kernel(const int* __restrict__ src,
                                                   const int* __restrict__ dst,
                                                   int* __restrict__ cursor,
                                                   int* __restrict__ ssrc) {
  int e = blockIdx.x * 256 + threadIdx.x;
  if (e < N_EDGES) {
    int pos = atomicAdd(&cursor[dst[e]], 1);
    ssrc[pos] = src[e];
  }
}

// ---------------- W prep: split fp32 W into bf16 hi/lo, TRANSPOSED (wt[col][k]) ----------------
// B-fragment loads then become 16B-contiguous per lane.

__global__ __launch_bounds__(256) void prep_w_kernel(
    const float* __restrict__ W0, const float* __restrict__ W1, const float* __restrict__ W2,
    unsigned short* __restrict__ wthi, unsigned short* __restrict__ wtlo) {
  int idx = blockIdx.x * 256 + threadIdx.x;  // 3 * 128 * 128
  if (idx >= 3 * FEAT * FEAT) return;
  int l = idx >> 14, rem = idx & 16383;
  int col = rem >> 7, k = rem & 127;
  const float* W = (l == 0) ? W0 : ((l == 1) ? W1 : W2);
  float v = W[k * FEAT + col];               // W is [k][col]
  unsigned short hi = f2bf(v);
  unsigned short lo = f2bf(v - bf2f(hi));
  wthi[(l * FEAT + col) * FEAT + k] = hi;
  wtlo[(l * FEAT + col) * FEAT + k] = lo;
}

// ---------------- GEMM via split-bf16 MFMA: h = act(in) @ W, fused el/er ----------------
// a*b ~= a_hi*b_hi + a_hi*b_lo + a_lo*b_hi (drop lo*lo, ~2^-18 rel) -> fp32-grade result
// on the 2.5PF bf16 matrix pipe. No LDS: A fragments loaded 32B/lane from global,
// B fragments 16B/lane from pre-transposed wt (64KB, L1/L2-resident).
// mfma_f32_16x16x32_bf16 layouts: A row=lane&15, k=(lane>>4)*8+e; B col=lane&15, same k;
// D col=lane&15, row=(lane>>4)*4+reg  [m89/m91-verified].

__global__ __launch_bounds__(256) void gemm_mfma_kernel(
    const float* __restrict__ in,
    const unsigned short* __restrict__ wthi, const unsigned short* __restrict__ wtlo,
    const float* __restrict__ al, const float* __restrict__ ar,
    float* __restrict__ h, float* __restrict__ el, float* __restrict__ er,
    int applyRelu)
{
  const int tid = threadIdx.x;
  const int wave = tid >> 6, lane = tid & 63;
  const int lrow = lane & 15, lkb = lane >> 4;
  const int arow_i = blockIdx.x * 64 + wave * 16 + lrow;   // this lane's A row
  const bool avalid = arow_i < N_NODES;

  // ---- load A row fragments: 4 k-blocks x 8 fp32, split to bf16 hi/lo ----
  bf16x8 ahi[4], alo[4];
  const float* arow = in + (size_t)arow_i * FEAT;
#pragma unroll
  for (int kb = 0; kb < 4; ++kb) {
    float a[8];
    if (avalid) {
      float4 v0 = *(const float4*)(arow + kb * 32 + lkb * 8);
      float4 v1 = *(const float4*)(arow + kb * 32 + lkb * 8 + 4);
      a[0] = v0.x; a[1] = v0.y; a[2] = v0.z; a[3] = v0.w;
      a[4] = v1.x; a[5] = v1.y; a[6] = v1.z; a[7] = v1.w;
    } else {
#pragma unroll
      for (int e = 0; e < 8; ++e) a[e] = 0.f;
    }
    if (applyRelu) {
#pragma unroll
      for (int e = 0; e < 8; ++e) a[e] = fmaxf(a[e], 0.f);
    }
#pragma unroll
    for (int e = 0; e < 8; ++e) {
      unsigned short hb = f2bf(a[e]);
      ahi[kb][e] = (short)hb;
      alo[kb][e] = (short)f2bf(a[e] - bf2f(hb));
    }
  }

  f32x4 acc[8];
#pragma unroll
  for (int ct = 0; ct < 8; ++ct)
#pragma unroll
    for (int r = 0; r < 4; ++r) acc[ct][r] = 0.f;

  // ---- 8 col-tiles x 4 k-blocks x 3 split-mfma ----
#pragma unroll
  for (int ct = 0; ct < 8; ++ct) {
    const int colb = ct * 16 + lrow;
#pragma unroll
    for (int kb = 0; kb < 4; ++kb) {
      const int off = colb * FEAT + kb * 32 + lkb * 8;
      bf16x8 bhi = *(const bf16x8*)(wthi + off);
      bf16x8 blo = *(const bf16x8*)(wtlo + off);
      acc[ct] = __builtin_amdgcn_mfma_f32_16x16x32_bf16(ahi[kb], bhi, acc[ct], 0, 0, 0);
      acc[ct] = __builtin_amdgcn_mfma_f32_16x16x32_bf16(ahi[kb], blo, acc[ct], 0, 0, 0);
      acc[ct] = __builtin_amdgcn_mfma_f32_16x16x32_bf16(alo[kb], bhi, acc[ct], 0, 0, 0);
    }
  }

  // ---- epilogue: write h, fused el/er (reduce over 16 col-lanes) ----
  float alv[8], arv[8];
#pragma unroll
  for (int ct = 0; ct < 8; ++ct) { alv[ct] = al[ct * 16 + lrow]; arv[ct] = ar[ct * 16 + lrow]; }

  const int obase = blockIdx.x * 64 + wave * 16 + lkb * 4;
#pragma unroll
  for (int r = 0; r < 4; ++r) {
    const int grow = obase + r;
    const bool gv = grow < N_NODES;      // uniform within each 16-lane shfl group
    float pel = 0.f, per_ = 0.f;
    if (gv) {
      float* hrow = h + (size_t)grow * FEAT;
#pragma unroll
      for (int ct = 0; ct < 8; ++ct) {
        float v = acc[ct][r];
        hrow[ct * 16 + lrow] = v;
        pel  = fmaf(v, alv[ct], pel);
        per_ = fmaf(v, arv[ct], per_);
      }
    }
#pragma unroll
    for (int mask = 8; mask >= 1; mask >>= 1) {
      pel  += __shfl_xor(pel, mask);
      per_ += __shfl_xor(per_, mask);
    }
    if (gv && lrow == 0) { el[grow] = pel; er[grow] = per_; }
  }
}

// ---------------- edge softmax + aggregate (unchanged from R4) ----------------

__global__ __launch_bounds__(256) void agg_kernel(
    const float* __restrict__ h, const float* __restrict__ el,
    const float* __restrict__ er, const int* __restrict__ offs,
    const int* __restrict__ ssrc, const float* __restrict__ bias,
    float* __restrict__ out)
{
  const int wid = (blockIdx.x * 256 + threadIdx.x) >> 6;  // node id, one wave each
  const int lane = threadIdx.x & 63;
  if (wid >= N_NODES) return;

  const int beg = offs[wid], end = offs[wid + 1];
  const float erd = er[wid];
  const float2* __restrict__ h2 = (const float2*)h;

  float2 acc = make_float2(0.f, 0.f);
  float denom = 0.f;
  float m = -1e30f;

  for (int base = beg; base < end; base += 64) {
    const int n = min(64, end - base);

    int s = 0;
    float e = -1e30f;
    if (lane < n) {
      s = ssrc[base + lane];
      float t = el[s] + erd;
      e = t > 0.f ? t : NEG_SLOPE * t;
    }

    float cm = e;
#pragma unroll
    for (int mask = 32; mask > 0; mask >>= 1) cm = fmaxf(cm, __shfl_xor(cm, mask));
    if (cm > m) {
      float scale = __expf(m - cm);
      acc.x *= scale; acc.y *= scale; denom *= scale;
      m = cm;
    }

    float ex = (lane < n) ? __expf(e - m) : 0.f;
    float dsum = ex;
#pragma unroll
    for (int mask = 32; mask > 0; mask >>= 1) dsum += __shfl_xor(dsum, mask);
    denom += dsum;

    int j = 0;
    for (; j + 4 <= n; j += 4) {
      int   s0 = __shfl(s, j),      s1 = __shfl(s, j + 1);
      int   s2 = __shfl(s, j + 2),  s3 = __shfl(s, j + 3);
      float e0 = __shfl(ex, j),     e1 = __shfl(ex, j + 1);
      float e2 = __shfl(ex, j + 2), e3 = __shfl(ex, j + 3);
      float2 v0 = h2[(s0 << 6) + lane];
      float2 v1 = h2[(s1 << 6) + lane];
      float2 v2 = h2[(s2 << 6) + lane];
      float2 v3 = h2[(s3 << 6) + lane];
      acc.x = fmaf(e0, v0.x, acc.x); acc.y = fmaf(e0, v0.y, acc.y);
      acc.x = fmaf(e1, v1.x, acc.x); acc.y = fmaf(e1, v1.y, acc.y);
      acc.x = fmaf(e2, v2.x, acc.x); acc.y = fmaf(e2, v2.y, acc.y);
      acc.x = fmaf(e3, v3.x, acc.x); acc.y = fmaf(e3, v3.y, acc.y);
    }
    for (; j < n; ++j) {
      int   sj = __shfl(s, j);
      float ej = __shfl(ex, j);
      float2 v = h2[(sj << 6) + lane];
      acc.x = fmaf(ej, v.x, acc.x); acc.y = fmaf(ej, v.y, acc.y);
    }
  }

  float inv = denom > 0.f ? 1.f / denom : 0.f;   // deg==0 -> out = bias
  float2 bv = ((const float2*)bias)[lane];
  float2 o = make_float2(fmaf(acc.x, inv, bv.x), fmaf(acc.y, inv, bv.y));
  ((float2*)out)[(wid << 6) + lane] = o;
}

// ---------------- launch ----------------

extern "C" void kernel_launch(void* const* d_in, const int* in_sizes, int n_in,
                              void* d_out, int out_size, void* d_ws, size_t ws_size,
                              hipStream_t stream) {
  const float* x  = (const float*)d_in[0];
  const int* src  = (const int*)d_in[1];
  const int* dst  = (const int*)d_in[2];
  const float* W[3]  = {(const float*)d_in[3],  (const float*)d_in[7],  (const float*)d_in[11]};
  const float* al[3] = {(const float*)d_in[4],  (const float*)d_in[8],  (const float*)d_in[12]};
  const float* ar[3] = {(const float*)d_in[5],  (const float*)d_in[9],  (const float*)d_in[13]};
  const float* b[3]  = {(const float*)d_in[6],  (const float*)d_in[10], (const float*)d_in[14]};

  // workspace layout (~29 MB); d_out doubles as the inter-layer ping buffer
  float* hW   = (float*)d_ws;           // 6,400,000 f
  float* el   = hW + 6400000;           // 50,016 f
  float* er   = el + 50016;             // 50,016 f
  int*   cnt  = (int*)(er + 50016);     // 50,016 i
  int*   offs = cnt + 50016;            // 50,016 i
  int*   part = offs + 50016;           // 256 i
  int*   ssrc = part + 256;             // 625,000 i
  unsigned short* wthi = (unsigned short*)(ssrc + 625000);  // 3*16384 bf16
  unsigned short* wtlo = wthi + 3 * FEAT * FEAT;            // 3*16384 bf16

  // ---- W split/transpose + CSR build (every call: no cross-call state) ----
  prep_w_kernel<<<(3 * FEAT * FEAT + 255) / 256, 256, 0, stream>>>(W[0], W[1], W[2], wthi, wtlo);
  hipMemsetAsync(cnt, 0, N_NODES * sizeof(int), stream);
  hist_kernel<<<(N_EDGES + 255) / 256, 256, 0, stream>>>(dst, cnt);
  scan_part_kernel<<<NB_SCAN, 256, 0, stream>>>(cnt, part);
  scan_top_kernel<<<1, 256, 0, stream>>>(part, offs);
  scan_down_kernel<<<NB_SCAN, 256, 0, stream>>>(cnt, part, offs);
  fill_kernel<<<(N_EDGES + 255) / 256, 256, 0, stream>>>(src, dst, cnt, ssrc);

  const int gemm_grid = (N_NODES + 63) / 64;       // 782 blocks, 64 rows each
  const int agg_grid  = (N_NODES + 3) / 4;         // 12500 (4 waves/block)
  float* outf = (float*)d_out;

  for (int l = 0; l < 3; ++l) {
    const float* lin = (l == 0) ? x : outf;        // relu applied on load for l>0
    gemm_mfma_kernel<<<gemm_grid, 256, 0, stream>>>(
        lin, wthi + l * FEAT * FEAT, wtlo + l * FEAT * FEAT,
        al[l], ar[l], hW, el, er, l > 0 ? 1 : 0);
    agg_kernel<<<agg_grid, 256, 0, stream>>>(hW, el, er, offs, ssrc, b[l], outf);
  }
}

// Round 6
// 236.688 us; speedup vs baseline: 1.4337x; 1.4337x over previous
//
#include <hip/hip_runtime.h>
#include <hip/hip_fp16.h>

#define N_NODES 50000
#define N_EDGES 625000
#define FEAT 128
#define NEG_SLOPE 0.2f
#define NB_SCAN 196   // ceil(50000/256)

typedef __attribute__((ext_vector_type(8))) short bf16x8;
typedef __attribute__((ext_vector_type(4))) float f32x4;

__device__ __forceinline__ unsigned short f2bf(float f) {
  unsigned u = __float_as_uint(f);
  u += 0x7fffu + ((u >> 16) & 1u);        // round-to-nearest-even
  return (unsigned short)(u >> 16);
}
__device__ __forceinline__ float bf2f(unsigned short s) {
  return __uint_as_float(((unsigned)s) << 16);
}

// ---------------- CSR build ----------------

__global__ __launch_bounds__(256) void hist_kernel(const int* __restrict__ dst,
                                                   int* __restrict__ cnt) {
  int e = blockIdx.x * 256 + threadIdx.x;
  if (e < N_EDGES) atomicAdd(&cnt[dst[e]], 1);
}

__global__ __launch_bounds__(256) void scan_part_kernel(const int* __restrict__ cnt,
                                                        int* __restrict__ part) {
  __shared__ int s[256];
  int i = blockIdx.x * 256 + threadIdx.x;
  s[threadIdx.x] = (i < N_NODES) ? cnt[i] : 0;
  __syncthreads();
  for (int o = 128; o > 0; o >>= 1) {
    if (threadIdx.x < o) s[threadIdx.x] += s[threadIdx.x + o];
    __syncthreads();
  }
  if (threadIdx.x == 0) part[blockIdx.x] = s[0];
}

__global__ __launch_bounds__(256) void scan_top_kernel(int* __restrict__ part,
                                                       int* __restrict__ offs) {
  __shared__ int s[256];
  int tid = threadIdx.x;
  int v = (tid < NB_SCAN) ? part[tid] : 0;
  s[tid] = v;
  __syncthreads();
  for (int o = 1; o < 256; o <<= 1) {
    int t = (tid >= o) ? s[tid - o] : 0;
    __syncthreads();
    s[tid] += t;
    __syncthreads();
  }
  if (tid < NB_SCAN) part[tid] = s[tid] - v;  // exclusive scan of block sums
  if (tid == 255) offs[N_NODES] = s[255];     // total (= N_EDGES)
}

__global__ __launch_bounds__(256) void scan_down_kernel(int* __restrict__ cnt,
                                                        const int* __restrict__ part,
                                                        int* __restrict__ offs) {
  __shared__ int s[256];
  int tid = threadIdx.x;
  int i = blockIdx.x * 256 + tid;
  int v = (i < N_NODES) ? cnt[i] : 0;
  s[tid] = v;
  __syncthreads();
  for (int o = 1; o < 256; o <<= 1) {
    int t = (tid >= o) ? s[tid - o] : 0;
    __syncthreads();
    s[tid] += t;
    __syncthreads();
  }
  if (i < N_NODES) {
    int excl = s[tid] - v + part[blockIdx.x];
    offs[i] = excl;
    cnt[i] = excl;  // becomes the fill cursor
  }
}

__global__ __launch_bounds__(256) void fill_kernel(const int* __restrict__ src,
                                                   const int* __restrict__ dst,
                                                   int* __restrict__ cursor,
                                                   int* __restrict__ ssrc) {
  int e = blockIdx.x * 256 + threadIdx.x;
  if (e < N_EDGES) {
    int pos = atomicAdd(&cursor[dst[e]], 1);
    ssrc[pos] = src[e];
  }
}

// ---------------- W prep: split fp32 W into bf16 hi/lo in FRAGMENT-MAJOR order ----------------
// Storage: wf[layer][ct][kb][lane][e] so each (ct,kb) B-fragment is one fully
// coalesced 1KB dwordx4 wave load in the GEMM. B layout for mfma_16x16x32_bf16:
// col = lane&15, k = kb*32 + (lane>>4)*8 + e.

__global__ __launch_bounds__(256) void prep_w_kernel(
    const float* __restrict__ W0, const float* __restrict__ W1, const float* __restrict__ W2,
    unsigned short* __restrict__ wfhi, unsigned short* __restrict__ wflo) {
  int idx = blockIdx.x * 256 + threadIdx.x;  // 3 * 16384
  if (idx >= 3 * FEAT * FEAT) return;
  int l = idx >> 14, rem = idx & 16383;
  int e = rem & 7, lane = (rem >> 3) & 63, kb = (rem >> 9) & 3, ct = rem >> 11;
  int col = ct * 16 + (lane & 15);
  int k   = kb * 32 + (lane >> 4) * 8 + e;
  const float* W = (l == 0) ? W0 : ((l == 1) ? W1 : W2);
  float v = W[k * FEAT + col];               // W is [k][col]
  unsigned short hi = f2bf(v);
  wfhi[idx] = hi;
  wflo[idx] = f2bf(v - bf2f(hi));
}

// ---------------- GEMM via split-bf16 MFMA: h(fp16) = act(in) @ W, fused el/er ----------------
// a*b ~= a_hi*b_hi + a_hi*b_lo + a_lo*b_hi (drop lo*lo) -> fp32-grade on the bf16 pipe.
// A: 32B/lane coalesced from global. B: fragment-major, 1KB/wave coalesced loads.
// D layout: col=lane&15, row=(lane>>4)*4+reg [m89/m91]. h written as fp16 (agg-only consumer).

__global__ __launch_bounds__(256) void gemm_mfma_kernel(
    const float* __restrict__ in,
    const unsigned short* __restrict__ wfhi, const unsigned short* __restrict__ wflo,
    const float* __restrict__ al, const float* __restrict__ ar,
    __half* __restrict__ h, float* __restrict__ el, float* __restrict__ er,
    int applyRelu)
{
  const int tid = threadIdx.x;
  const int wave = tid >> 6, lane = tid & 63;
  const int lrow = lane & 15, lkb = lane >> 4;
  const int arow_i = blockIdx.x * 64 + wave * 16 + lrow;   // this lane's A row
  const bool avalid = arow_i < N_NODES;

  // ---- A row fragments: 4 k-blocks x 8 fp32, split to bf16 hi/lo ----
  bf16x8 ahi[4], alo[4];
  const float* arow = in + (size_t)arow_i * FEAT;
#pragma unroll
  for (int kb = 0; kb < 4; ++kb) {
    float a[8];
    if (avalid) {
      float4 v0 = *(const float4*)(arow + kb * 32 + lkb * 8);
      float4 v1 = *(const float4*)(arow + kb * 32 + lkb * 8 + 4);
      a[0] = v0.x; a[1] = v0.y; a[2] = v0.z; a[3] = v0.w;
      a[4] = v1.x; a[5] = v1.y; a[6] = v1.z; a[7] = v1.w;
    } else {
#pragma unroll
      for (int e = 0; e < 8; ++e) a[e] = 0.f;
    }
    if (applyRelu) {
#pragma unroll
      for (int e = 0; e < 8; ++e) a[e] = fmaxf(a[e], 0.f);
    }
#pragma unroll
    for (int e = 0; e < 8; ++e) {
      unsigned short hb = f2bf(a[e]);
      ahi[kb][e] = (short)hb;
      alo[kb][e] = (short)f2bf(a[e] - bf2f(hb));
    }
  }

  f32x4 acc[8];
#pragma unroll
  for (int ct = 0; ct < 8; ++ct)
#pragma unroll
    for (int r = 0; r < 4; ++r) acc[ct][r] = 0.f;

  // ---- 8 col-tiles x 4 k-blocks x 3 split-mfma; B loads fully coalesced ----
#pragma unroll
  for (int ct = 0; ct < 8; ++ct) {
#pragma unroll
    for (int kb = 0; kb < 4; ++kb) {
      const int off = (ct * 4 + kb) * 512 + lane * 8;
      bf16x8 bhi = *(const bf16x8*)(wfhi + off);
      bf16x8 blo = *(const bf16x8*)(wflo + off);
      acc[ct] = __builtin_amdgcn_mfma_f32_16x16x32_bf16(ahi[kb], bhi, acc[ct], 0, 0, 0);
      acc[ct] = __builtin_amdgcn_mfma_f32_16x16x32_bf16(ahi[kb], blo, acc[ct], 0, 0, 0);
      acc[ct] = __builtin_amdgcn_mfma_f32_16x16x32_bf16(alo[kb], bhi, acc[ct], 0, 0, 0);
    }
  }

  // ---- epilogue: write h (fp16), fused el/er (reduce over 16 col-lanes) ----
  float alv[8], arv[8];
#pragma unroll
  for (int ct = 0; ct < 8; ++ct) { alv[ct] = al[ct * 16 + lrow]; arv[ct] = ar[ct * 16 + lrow]; }

  const int obase = blockIdx.x * 64 + wave * 16 + lkb * 4;
#pragma unroll
  for (int r = 0; r < 4; ++r) {
    const int grow = obase + r;
    const bool gv = grow < N_NODES;      // uniform within each 16-lane shfl group
    float pel = 0.f, per_ = 0.f;
    if (gv) {
      __half* hrow = h + (size_t)grow * FEAT;
#pragma unroll
      for (int ct = 0; ct < 8; ++ct) {
        float v = acc[ct][r];
        hrow[ct * 16 + lrow] = __float2half_rn(v);
        pel  = fmaf(v, alv[ct], pel);
        per_ = fmaf(v, arv[ct], per_);
      }
    }
#pragma unroll
    for (int mask = 8; mask >= 1; mask >>= 1) {
      pel  += __shfl_xor(pel, mask);
      per_ += __shfl_xor(per_, mask);
    }
    if (gv && lrow == 0) { el[grow] = pel; er[grow] = per_; }
  }
}

// ---------------- edge softmax + aggregate: one wave per destination node ----------------
// fp16 h gather (halves traffic + resident set); accumulation stays fp32.

__global__ __launch_bounds__(256) void agg_kernel(
    const __half* __restrict__ h, const float* __restrict__ el,
    const float* __restrict__ er, const int* __restrict__ offs,
    const int* __restrict__ ssrc, const float* __restrict__ bias,
    float* __restrict__ out)
{
  const int wid = (blockIdx.x * 256 + threadIdx.x) >> 6;  // node id, one wave each
  const int lane = threadIdx.x & 63;
  if (wid >= N_NODES) return;

  const int beg = offs[wid], end = offs[wid + 1];
  const float erd = er[wid];
  const __half2* __restrict__ hh = (const __half2*)h;     // row = 64 half2

  float2 acc = make_float2(0.f, 0.f);
  float denom = 0.f;
  float m = -1e30f;

  for (int base = beg; base < end; base += 64) {
    const int n = min(64, end - base);

    // load this chunk's edges once: src id + attention logit, lane-strided
    int s = 0;
    float e = -1e30f;
    if (lane < n) {
      s = ssrc[base + lane];
      float t = el[s] + erd;
      e = t > 0.f ? t : NEG_SLOPE * t;
    }

    // chunk max -> running max with rescale of prior accumulation
    float cm = e;
#pragma unroll
    for (int mask = 32; mask > 0; mask >>= 1) cm = fmaxf(cm, __shfl_xor(cm, mask));
    if (cm > m) {
      float scale = __expf(m - cm);   // first chunk: exp(-huge)=0, acc/denom already 0
      acc.x *= scale; acc.y *= scale; denom *= scale;
      m = cm;
    }

    float ex = (lane < n) ? __expf(e - m) : 0.f;
    float dsum = ex;
#pragma unroll
    for (int mask = 32; mask > 0; mask >>= 1) dsum += __shfl_xor(dsum, mask);
    denom += dsum;

    // feature gather: j uniform -> shfl broadcast; 4 independent loads in flight
    int j = 0;
    for (; j + 4 <= n; j += 4) {
      int   s0 = __shfl(s, j),      s1 = __shfl(s, j + 1);
      int   s2 = __shfl(s, j + 2),  s3 = __shfl(s, j + 3);
      float e0 = __shfl(ex, j),     e1 = __shfl(ex, j + 1);
      float e2 = __shfl(ex, j + 2), e3 = __shfl(ex, j + 3);
      float2 v0 = __half22float2(hh[(s0 << 6) + lane]);
      float2 v1 = __half22float2(hh[(s1 << 6) + lane]);
      float2 v2 = __half22float2(hh[(s2 << 6) + lane]);
      float2 v3 = __half22float2(hh[(s3 << 6) + lane]);
      acc.x = fmaf(e0, v0.x, acc.x); acc.y = fmaf(e0, v0.y, acc.y);
      acc.x = fmaf(e1, v1.x, acc.x); acc.y = fmaf(e1, v1.y, acc.y);
      acc.x = fmaf(e2, v2.x, acc.x); acc.y = fmaf(e2, v2.y, acc.y);
      acc.x = fmaf(e3, v3.x, acc.x); acc.y = fmaf(e3, v3.y, acc.y);
    }
    for (; j < n; ++j) {
      int   sj = __shfl(s, j);
      float ej = __shfl(ex, j);
      float2 v = __half22float2(hh[(sj << 6) + lane]);
      acc.x = fmaf(ej, v.x, acc.x); acc.y = fmaf(ej, v.y, acc.y);
    }
  }

  float inv = denom > 0.f ? 1.f / denom : 0.f;   // deg==0 -> out = bias
  float2 bv = ((const float2*)bias)[lane];
  float2 o = make_float2(fmaf(acc.x, inv, bv.x), fmaf(acc.y, inv, bv.y));
  ((float2*)out)[(wid << 6) + lane] = o;
}

// ---------------- launch ----------------

extern "C" void kernel_launch(void* const* d_in, const int* in_sizes, int n_in,
                              void* d_out, int out_size, void* d_ws, size_t ws_size,
                              hipStream_t stream) {
  const float* x  = (const float*)d_in[0];
  const int* src  = (const int*)d_in[1];
  const int* dst  = (const int*)d_in[2];
  const float* W[3]  = {(const float*)d_in[3],  (const float*)d_in[7],  (const float*)d_in[11]};
  const float* al[3] = {(const float*)d_in[4],  (const float*)d_in[8],  (const float*)d_in[12]};
  const float* ar[3] = {(const float*)d_in[5],  (const float*)d_in[9],  (const float*)d_in[13]};
  const float* b[3]  = {(const float*)d_in[6],  (const float*)d_in[10], (const float*)d_in[14]};

  // workspace layout (~16.5 MB); d_out doubles as the inter-layer ping buffer
  __half* hH  = (__half*)d_ws;                       // 6,400,000 half (12.8 MB)
  float*  el  = (float*)(hH + 6400000);              // 50,016 f
  float*  er  = el + 50016;                          // 50,016 f
  int*    cnt = (int*)(er + 50016);                  // 50,016 i
  int*    offs = cnt + 50016;                        // 50,016 i
  int*    part = offs + 50016;                       // 256 i
  int*    ssrc = part + 256;                         // 625,000 i
  unsigned short* wfhi = (unsigned short*)(ssrc + 625000);  // 3*16384 bf16 (fragment-major)
  unsigned short* wflo = wfhi + 3 * FEAT * FEAT;            // 3*16384 bf16

  // ---- W split/permute + CSR build (every call: no cross-call state) ----
  prep_w_kernel<<<(3 * FEAT * FEAT + 255) / 256, 256, 0, stream>>>(W[0], W[1], W[2], wfhi, wflo);
  hipMemsetAsync(cnt, 0, N_NODES * sizeof(int), stream);
  hist_kernel<<<(N_EDGES + 255) / 256, 256, 0, stream>>>(dst, cnt);
  scan_part_kernel<<<NB_SCAN, 256, 0, stream>>>(cnt, part);
  scan_top_kernel<<<1, 256, 0, stream>>>(part, offs);
  scan_down_kernel<<<NB_SCAN, 256, 0, stream>>>(cnt, part, offs);
  fill_kernel<<<(N_EDGES + 255) / 256, 256, 0, stream>>>(src, dst, cnt, ssrc);

  const int gemm_grid = (N_NODES + 63) / 64;       // 782 blocks, 64 rows each
  const int agg_grid  = (N_NODES + 3) / 4;         // 12500 (4 waves/block)
  float* outf = (float*)d_out;

  for (int l = 0; l < 3; ++l) {
    const float* lin = (l == 0) ? x : outf;        // relu applied on load for l>0
    gemm_mfma_kernel<<<gemm_grid, 256, 0, stream>>>(
        lin, wfhi + l * FEAT * FEAT, wflo + l * FEAT * FEAT,
        al[l], ar[l], hH, el, er, l > 0 ? 1 : 0);
    agg_kernel<<<agg_grid, 256, 0, stream>>>(hH, el, er, offs, ssrc, b[l], outf);
  }
}